// Round 5
// baseline (532.736 us; speedup 1.0000x reference)
//
#include <hip/hip_runtime.h>
#include <stdint.h>

typedef __bf16 bf16_t;
typedef __bf16 bf16x8 __attribute__((ext_vector_type(8)));
typedef __bf16 bf16x4v __attribute__((ext_vector_type(4)));
typedef float f32x4 __attribute__((ext_vector_type(4)));

#define AS_GLOBAL __attribute__((address_space(1)))
#define AS_LDS    __attribute__((address_space(3)))

static constexpr int NN   = 8192;   // nodes
static constexpr int DIN  = 512;
static constexpr int DOUT = 512;
static constexpr int SPLITK = 4;    // gemm1: 1024 blocks, ~3 resident/CU (VGPR-bound)

// 16B async global->LDS copy (global_load_lds_dwordx4).
__device__ __forceinline__ void async_cp16(const bf16_t* g, bf16_t* l) {
  __builtin_amdgcn_global_load_lds((AS_GLOBAL unsigned int*)g,
                                   (AS_LDS unsigned int*)l, 16, 0, 0);
}

// ---------------------------------------------------------------------------
// K1: d[i] = rsqrt(sum_k adj[i,k] + 1), adjb = bf16(adj). Unit-stride.
// ---------------------------------------------------------------------------
__global__ __launch_bounds__(256) void k_rowsum_convert(
    const float* __restrict__ adj, bf16_t* __restrict__ adjb,
    float* __restrict__ d) {
  const int row = blockIdx.x;
  const int t = threadIdx.x;
  const float4* rf4 = (const float4*)(adj + (size_t)row * NN);
  bf16_t* outp = adjb + (size_t)row * NN;
  float sum = 0.f;
#pragma unroll
  for (int c = 0; c < 8; ++c) {
    int f4i = c * 256 + t;               // 2048 float4 per row
    float4 a = rf4[f4i];
    sum += a.x + a.y + a.z + a.w;
    bf16x4v o;
    o[0] = (bf16_t)a.x; o[1] = (bf16_t)a.y; o[2] = (bf16_t)a.z; o[3] = (bf16_t)a.w;
    *(bf16x4v*)(outp + f4i * 4) = o;
  }
#pragma unroll
  for (int off = 32; off > 0; off >>= 1) sum += __shfl_down(sum, off);
  __shared__ float red[4];
  if ((t & 63) == 0) red[t >> 6] = sum;
  __syncthreads();
  if (t == 0) {
    float s = red[0] + red[1] + red[2] + red[3] + 1.0f;  // +1 for identity
    d[row] = rsqrtf(s);
  }
}

// ---------------------------------------------------------------------------
// K2: xsT[j][k] = bf16(d[k] * x[k][j])   (512 x 8192, k contiguous)
// ---------------------------------------------------------------------------
__global__ __launch_bounds__(256) void k_make_xsT(
    const float* __restrict__ x, const float* __restrict__ d,
    bf16_t* __restrict__ xsT) {
  __shared__ bf16_t T[64][72];  // +8 pad: conflict-free column reads
  const int t = threadIdx.x;
  const int k0 = blockIdx.x * 64, j0 = blockIdx.y * 64;
#pragma unroll
  for (int it = 0; it < 4; ++it) {
    int idx = it * 256 + t;
    int r = idx >> 4, c = idx & 15;
    float4 v = *(const float4*)(x + (size_t)(k0 + r) * DIN + j0 + c * 4);
    float s = d[k0 + r];
    T[r][c * 4 + 0] = (bf16_t)(v.x * s);
    T[r][c * 4 + 1] = (bf16_t)(v.y * s);
    T[r][c * 4 + 2] = (bf16_t)(v.z * s);
    T[r][c * 4 + 3] = (bf16_t)(v.w * s);
  }
  __syncthreads();
#pragma unroll
  for (int it = 0; it < 2; ++it) {
    int idx = it * 256 + t;
    int j = idx >> 3, kb = idx & 7;
    bf16x8 o;
#pragma unroll
    for (int e = 0; e < 8; ++e) o[e] = T[kb * 8 + e][j];
    *(bf16x8*)(xsT + (size_t)(j0 + j) * NN + k0 + kb * 8) = o;
  }
}

// ---------------------------------------------------------------------------
// K3: Wb = bf16(W)
// ---------------------------------------------------------------------------
__global__ __launch_bounds__(256) void k_convert_w(
    const float* __restrict__ W, bf16_t* __restrict__ Wb) {
  int idx = blockIdx.x * 256 + threadIdx.x;
  float4 v = *(const float4*)(W + (size_t)idx * 4);
  bf16x4v o;
  o[0] = (bf16_t)v.x; o[1] = (bf16_t)v.y; o[2] = (bf16_t)v.z; o[3] = (bf16_t)v.w;
  *(bf16x4v*)(Wb + (size_t)idx * 4) = o;
}

// ---------------------------------------------------------------------------
// GEMM core: C[128x128] += A[m0.., kS:kE] * B[n0.., :]^T   (NT, bf16)
// 256 thr = 4 waves 2x2, wave 64x64 via 4x4 frags of 16x16x32 bf16.
// XOR-swizzled LDS (chunk c of row r at physical c^(r&7)): staging lane
// permutes the global source chunk (coalescing kept), frag reads XOR back.
// NOTE: no min-waves launch bound anywhere — VGPR ~164 (m97-class) must not
// be capped or the acc/staging regs spill into the K-loop (R3 confound).
// ---------------------------------------------------------------------------
__device__ __forceinline__ void gemm_tile_128x128(
    const bf16_t* __restrict__ A, const bf16_t* __restrict__ B,
    int lda, int ldb, int m0, int n0, int kStart, int kEnd,
    bf16_t* As, bf16_t* Bs, f32x4 acc[4][4]) {
  const int t = threadIdx.x;
  const int lane = t & 63;
  const int wid = t >> 6;
  const int wm = wid >> 1, wn = wid & 1;
  const int lanelo = lane & 15, quad = lane >> 4;

  const int swz = (t & 7) ^ ((t >> 3) & 7);
  const bf16_t* gA = A + (size_t)(m0 + (t >> 3)) * lda + swz * 8 + kStart;
  const bf16_t* gB = B + (size_t)(n0 + (t >> 3)) * ldb + swz * 8 + kStart;
  bf16_t* lA = As + t * 8;
  bf16_t* lB = Bs + t * 8;

  const int xorc = lanelo & 7;

  for (int k0 = kStart; k0 < kEnd; k0 += 64) {
#pragma unroll
    for (int i = 0; i < 4; ++i) {
      async_cp16(gA + (size_t)(i * 32) * lda, lA + i * 2048);
      async_cp16(gB + (size_t)(i * 32) * ldb, lB + i * 2048);
    }
    gA += 64; gB += 64;
    __syncthreads();
#pragma unroll
    for (int kk = 0; kk < 2; ++kk) {
      const int pchunk = ((kk * 4 + quad) ^ xorc) * 8;
      bf16x8 av[4], bv[4];
#pragma unroll
      for (int f = 0; f < 4; ++f) {
        av[f] = *(const bf16x8*)(As + (wm * 64 + f * 16 + lanelo) * 64 + pchunk);
        bv[f] = *(const bf16x8*)(Bs + (wn * 64 + f * 16 + lanelo) * 64 + pchunk);
      }
#pragma unroll
      for (int fm = 0; fm < 4; ++fm)
#pragma unroll
        for (int fn = 0; fn < 4; ++fn)
          acc[fm][fn] = __builtin_amdgcn_mfma_f32_16x16x32_bf16(
              av[fm], bv[fn], acc[fm][fn], 0, 0, 0);
    }
    __syncthreads();
  }
}

// ---------------------------------------------------------------------------
// K4: gemm1 partials: part[kc][i][j] = sum_{k in chunk kc} adjb[i,k]*xsT[j,k]
// grid (64, 4, SPLITK) = 1024 blocks; VGPR-bound occupancy ~3 blocks/CU.
// ---------------------------------------------------------------------------
__global__ __launch_bounds__(256) void k_gemm1(
    const bf16_t* __restrict__ adjb, const bf16_t* __restrict__ xsT,
    float* __restrict__ part) {
  __shared__ bf16_t As[128 * 64];
  __shared__ bf16_t Bs[128 * 64];
  f32x4 acc[4][4];
  const f32x4 fzero = {0.f, 0.f, 0.f, 0.f};
#pragma unroll
  for (int a = 0; a < 4; ++a)
#pragma unroll
    for (int b = 0; b < 4; ++b) acc[a][b] = fzero;

  const int m0 = blockIdx.x * 128, n0 = blockIdx.y * 128;
  const int kc = blockIdx.z;
  const int kChunk = NN / SPLITK;           // 2048
  gemm_tile_128x128(adjb, xsT, NN, NN, m0, n0, kc * kChunk, (kc + 1) * kChunk,
                    As, Bs, acc);

  const int t = threadIdx.x;
  const int lane = t & 63, wid = t >> 6;
  const int wm = wid >> 1, wn = wid & 1;
  const int lanelo = lane & 15, quad = lane >> 4;
  float* outp = part + (size_t)kc * NN * DIN;
#pragma unroll
  for (int fm = 0; fm < 4; ++fm)
#pragma unroll
    for (int fn = 0; fn < 4; ++fn) {
      int gc = n0 + wn * 64 + fn * 16 + lanelo;
#pragma unroll
      for (int r = 0; r < 4; ++r) {
        int gr = m0 + wm * 64 + fm * 16 + quad * 4 + r;
        outp[(size_t)gr * DIN + gc] = acc[fm][fn][r];
      }
    }
}

// ---------------------------------------------------------------------------
// K5: support_bf16[i][j] = bf16( d[i]*(sum of SPLITK partials) + d[i]^2*x )
// ---------------------------------------------------------------------------
__global__ __launch_bounds__(256) void k_combine(
    const float* __restrict__ part, const float* __restrict__ d,
    const float* __restrict__ x, bf16_t* __restrict__ supB) {
  int idx = blockIdx.x * 256 + threadIdx.x;   // float4 index
  int i = idx >> 7;                           // 128 f4 per row
  float4 p = *(const float4*)(part + (size_t)idx * 4);
#pragma unroll
  for (int kc = 1; kc < SPLITK; ++kc) {
    float4 q = *(const float4*)(part + (size_t)kc * NN * DIN + (size_t)idx * 4);
    p.x += q.x; p.y += q.y; p.z += q.z; p.w += q.w;
  }
  float4 xv = *(const float4*)(x + (size_t)idx * 4);
  float di = d[i];
  float dii = di * di;
  bf16x4v o;
  o[0] = (bf16_t)(di * p.x + dii * xv.x);
  o[1] = (bf16_t)(di * p.y + dii * xv.y);
  o[2] = (bf16_t)(di * p.z + dii * xv.z);
  o[3] = (bf16_t)(di * p.w + dii * xv.w);
  *(bf16x4v*)(supB + (size_t)idx * 4) = o;
}

// ---------------------------------------------------------------------------
// K6: out = relu(supB @ Wb^T + bias), fp32 out.
// ---------------------------------------------------------------------------
__global__ __launch_bounds__(256) void k_gemm2(
    const bf16_t* __restrict__ supB, const bf16_t* __restrict__ Wb,
    const float* __restrict__ bias, float* __restrict__ outp) {
  __shared__ bf16_t As[128 * 64];
  __shared__ bf16_t Bs[128 * 64];
  f32x4 acc[4][4];
  const f32x4 fzero = {0.f, 0.f, 0.f, 0.f};
#pragma unroll
  for (int a = 0; a < 4; ++a)
#pragma unroll
    for (int b = 0; b < 4; ++b) acc[a][b] = fzero;

  const int m0 = blockIdx.x * 128, n0 = blockIdx.y * 128;
  gemm_tile_128x128(supB, Wb, DIN, DIN, m0, n0, 0, DIN, As, Bs, acc);

  const int t = threadIdx.x;
  const int lane = t & 63, wid = t >> 6;
  const int wm = wid >> 1, wn = wid & 1;
  const int lanelo = lane & 15, quad = lane >> 4;
#pragma unroll
  for (int fn = 0; fn < 4; ++fn) {
    int gc = n0 + wn * 64 + fn * 16 + lanelo;
    float bb = bias[gc];
#pragma unroll
    for (int fm = 0; fm < 4; ++fm)
#pragma unroll
      for (int r = 0; r < 4; ++r) {
        int gr = m0 + wm * 64 + fm * 16 + quad * 4 + r;
        float v = acc[fm][fn][r] + bb;
        outp[(size_t)gr * DOUT + gc] = v > 0.f ? v : 0.f;
      }
  }
}

// ---------------------------------------------------------------------------
extern "C" void kernel_launch(void* const* d_in, const int* in_sizes, int n_in,
                              void* d_out, int out_size, void* d_ws, size_t ws_size,
                              hipStream_t stream) {
  const float* x   = (const float*)d_in[0];   // (8192, 512)
  const float* adj = (const float*)d_in[1];   // (8192, 8192)
  const float* W   = (const float*)d_in[2];   // (512, 512) (out,in)
  const float* b   = (const float*)d_in[3];   // (512,)
  float* out = (float*)d_out;                 // (8192, 512) fp32

  char* ws = (char*)d_ws;
  bf16_t* adjb = (bf16_t*)(ws);                        // 134217728 (8192x8192 bf16)
  float*  part = (float*)(ws + 134217728);             // SPLITK x 16 MB fp32
  size_t  off  = 134217728 + (size_t)SPLITK * NN * DIN * 4;
  bf16_t* xsT  = (bf16_t*)(ws + off);                  // 8 MB (512x8192 bf16)
  bf16_t* supB = (bf16_t*)(ws + off + 8388608);        // 8 MB (8192x512 bf16)
  bf16_t* Wb   = (bf16_t*)(ws + off + 16777216);       // 0.5 MB
  float*  dvec = (float*)(ws + off + 17301504);        // 32 KB

  k_rowsum_convert<<<NN, 256, 0, stream>>>(adj, adjb, dvec);
  k_make_xsT<<<dim3(NN / 64, DIN / 64), 256, 0, stream>>>(x, dvec, xsT);
  k_convert_w<<<(DOUT * DIN) / 1024, 256, 0, stream>>>(W, Wb);
  k_gemm1<<<dim3(NN / 128, DIN / 128, SPLITK), 256, 0, stream>>>(adjb, xsT, part);
  k_combine<<<(NN * DIN) / 1024, 256, 0, stream>>>(part, dvec, x, supB);
  k_gemm2<<<dim3(NN / 128, DOUT / 128), 256, 0, stream>>>(supB, Wb, b, out);
}

// Round 6
// 518.345 us; speedup vs baseline: 1.0278x; 1.0278x over previous
//
#include <hip/hip_runtime.h>
#include <stdint.h>

typedef __bf16 bf16_t;
typedef __bf16 bf16x8 __attribute__((ext_vector_type(8)));
typedef __bf16 bf16x4v __attribute__((ext_vector_type(4)));
typedef float f32x16 __attribute__((ext_vector_type(16)));

#define AS_GLOBAL __attribute__((address_space(1)))
#define AS_LDS    __attribute__((address_space(3)))

static constexpr int NN   = 8192;   // nodes
static constexpr int DIN  = 512;
static constexpr int DOUT = 512;
static constexpr int SPLITK = 2;    // R2's measured-best; splitk4 regressed +14us (R5)

// 16B async global->LDS copy (global_load_lds_dwordx4).
__device__ __forceinline__ void async_cp16(const bf16_t* g, bf16_t* l) {
  __builtin_amdgcn_global_load_lds((AS_GLOBAL unsigned int*)g,
                                   (AS_LDS unsigned int*)l, 16, 0, 0);
}

// ---------------------------------------------------------------------------
// K1: d[i] = rsqrt(sum_k adj[i,k] + 1), adjb = bf16(adj). Unit-stride.
// ---------------------------------------------------------------------------
__global__ __launch_bounds__(256) void k_rowsum_convert(
    const float* __restrict__ adj, bf16_t* __restrict__ adjb,
    float* __restrict__ d) {
  const int row = blockIdx.x;
  const int t = threadIdx.x;
  const float4* rf4 = (const float4*)(adj + (size_t)row * NN);
  bf16_t* outp = adjb + (size_t)row * NN;
  float sum = 0.f;
#pragma unroll
  for (int c = 0; c < 8; ++c) {
    int f4i = c * 256 + t;               // 2048 float4 per row
    float4 a = rf4[f4i];
    sum += a.x + a.y + a.z + a.w;
    bf16x4v o;
    o[0] = (bf16_t)a.x; o[1] = (bf16_t)a.y; o[2] = (bf16_t)a.z; o[3] = (bf16_t)a.w;
    *(bf16x4v*)(outp + f4i * 4) = o;
  }
#pragma unroll
  for (int off = 32; off > 0; off >>= 1) sum += __shfl_down(sum, off);
  __shared__ float red[4];
  if ((t & 63) == 0) red[t >> 6] = sum;
  __syncthreads();
  if (t == 0) {
    float s = red[0] + red[1] + red[2] + red[3] + 1.0f;  // +1 for identity
    d[row] = rsqrtf(s);
  }
}

// ---------------------------------------------------------------------------
// K2: xsT[j][k] = bf16(d[k] * x[k][j])   (512 x 8192, k contiguous)
// ---------------------------------------------------------------------------
__global__ __launch_bounds__(256) void k_make_xsT(
    const float* __restrict__ x, const float* __restrict__ d,
    bf16_t* __restrict__ xsT) {
  __shared__ bf16_t T[64][72];  // +8 pad: conflict-free column reads
  const int t = threadIdx.x;
  const int k0 = blockIdx.x * 64, j0 = blockIdx.y * 64;
#pragma unroll
  for (int it = 0; it < 4; ++it) {
    int idx = it * 256 + t;
    int r = idx >> 4, c = idx & 15;
    float4 v = *(const float4*)(x + (size_t)(k0 + r) * DIN + j0 + c * 4);
    float s = d[k0 + r];
    T[r][c * 4 + 0] = (bf16_t)(v.x * s);
    T[r][c * 4 + 1] = (bf16_t)(v.y * s);
    T[r][c * 4 + 2] = (bf16_t)(v.z * s);
    T[r][c * 4 + 3] = (bf16_t)(v.w * s);
  }
  __syncthreads();
#pragma unroll
  for (int it = 0; it < 2; ++it) {
    int idx = it * 256 + t;
    int j = idx >> 3, kb = idx & 7;
    bf16x8 o;
#pragma unroll
    for (int e = 0; e < 8; ++e) o[e] = T[kb * 8 + e][j];
    *(bf16x8*)(xsT + (size_t)(j0 + j) * NN + k0 + kb * 8) = o;
  }
}

// ---------------------------------------------------------------------------
// K3: Wb = bf16(W)
// ---------------------------------------------------------------------------
__global__ __launch_bounds__(256) void k_convert_w(
    const float* __restrict__ W, bf16_t* __restrict__ Wb) {
  int idx = blockIdx.x * 256 + threadIdx.x;
  float4 v = *(const float4*)(W + (size_t)idx * 4);
  bf16x4v o;
  o[0] = (bf16_t)v.x; o[1] = (bf16_t)v.y; o[2] = (bf16_t)v.z; o[3] = (bf16_t)v.w;
  *(bf16x4v*)(Wb + (size_t)idx * 4) = o;
}

// ---------------------------------------------------------------------------
// GEMM core: C[128x128] += A[m0.., kS:kE] * B[n0.., :]^T   (NT, bf16)
// 256 thr = 4 waves 2x2, wave 64x64 via 2x2 frags of v_mfma_f32_32x32x16_bf16
// (2382 TF ubench vs 2075 for 16x16x32 — m06). Operand layout mirrors the
// verified 16x16x32 pattern: m=lane&31, k=(lane>>5)*8+j (8 contiguous bf16 =
// one b128). C/D: col=lane&31, row=(reg&3)+8*(reg>>2)+4*(lane>>5) [m74/m101].
// XOR-swizzled LDS (chunk c of row r at physical c^(r&7)): staging lane
// permutes its global source chunk (coalescing kept), frag reads XOR back ->
// uniform 8 lanes/bank-quad = b128 conflict floor.
// ---------------------------------------------------------------------------
__device__ __forceinline__ void gemm_tile_128x128(
    const bf16_t* __restrict__ A, const bf16_t* __restrict__ B,
    int lda, int ldb, int m0, int n0, int kStart, int kEnd,
    bf16_t* As, bf16_t* Bs, f32x16 acc[2][2]) {
  const int t = threadIdx.x;
  const int lane = t & 63;
  const int wid = t >> 6;
  const int wm = wid >> 1, wn = wid & 1;
  const int l32 = lane & 31, half = lane >> 5;

  const int swz = (t & 7) ^ ((t >> 3) & 7);
  const bf16_t* gA = A + (size_t)(m0 + (t >> 3)) * lda + swz * 8 + kStart;
  const bf16_t* gB = B + (size_t)(n0 + (t >> 3)) * ldb + swz * 8 + kStart;
  bf16_t* lA = As + t * 8;
  bf16_t* lB = Bs + t * 8;

  const int xorc = lane & 7;

  for (int k0 = kStart; k0 < kEnd; k0 += 64) {
#pragma unroll
    for (int i = 0; i < 4; ++i) {
      async_cp16(gA + (size_t)(i * 32) * lda, lA + i * 2048);
      async_cp16(gB + (size_t)(i * 32) * ldb, lB + i * 2048);
    }
    gA += 64; gB += 64;
    __syncthreads();   // drains vmcnt(0) -> staged tiles visible
#pragma unroll
    for (int ks = 0; ks < 4; ++ks) {         // 4 K-steps of 16
      const int pchunk = ((ks * 2 + half) ^ xorc) * 8;
      bf16x8 av[2], bv[2];
#pragma unroll
      for (int f = 0; f < 2; ++f) {
        av[f] = *(const bf16x8*)(As + (wm * 64 + f * 32 + l32) * 64 + pchunk);
        bv[f] = *(const bf16x8*)(Bs + (wn * 64 + f * 32 + l32) * 64 + pchunk);
      }
#pragma unroll
      for (int fm = 0; fm < 2; ++fm)
#pragma unroll
        for (int fn = 0; fn < 2; ++fn)
          acc[fm][fn] = __builtin_amdgcn_mfma_f32_32x32x16_bf16(
              av[fm], bv[fn], acc[fm][fn], 0, 0, 0);
    }
    __syncthreads();   // protect LDS reuse
  }
}

// ---------------------------------------------------------------------------
// K4: gemm1 partials: part[kc][i][j] = sum_{k in chunk kc} adjb[i,k]*xsT[j,k]
// grid (64, 4, SPLITK) = 512 blocks, 2 resident/CU.
// ---------------------------------------------------------------------------
__global__ __launch_bounds__(256) void k_gemm1(
    const bf16_t* __restrict__ adjb, const bf16_t* __restrict__ xsT,
    float* __restrict__ part) {
  __shared__ bf16_t As[128 * 64];
  __shared__ bf16_t Bs[128 * 64];
  f32x16 acc[2][2];
#pragma unroll
  for (int a = 0; a < 2; ++a)
#pragma unroll
    for (int b = 0; b < 2; ++b)
#pragma unroll
      for (int r = 0; r < 16; ++r) acc[a][b][r] = 0.f;

  const int m0 = blockIdx.x * 128, n0 = blockIdx.y * 128;
  const int kc = blockIdx.z;
  const int kChunk = NN / SPLITK;           // 4096
  gemm_tile_128x128(adjb, xsT, NN, NN, m0, n0, kc * kChunk, (kc + 1) * kChunk,
                    As, Bs, acc);

  const int t = threadIdx.x;
  const int lane = t & 63, wid = t >> 6;
  const int wm = wid >> 1, wn = wid & 1;
  const int l32 = lane & 31, half = lane >> 5;
  float* outp = part + (size_t)kc * NN * DIN;
#pragma unroll
  for (int fm = 0; fm < 2; ++fm)
#pragma unroll
    for (int fn = 0; fn < 2; ++fn) {
      int gc = n0 + wn * 64 + fn * 32 + l32;
#pragma unroll
      for (int reg = 0; reg < 16; ++reg) {
        int gr = m0 + wm * 64 + fm * 32 + (reg & 3) + 8 * (reg >> 2) + 4 * half;
        outp[(size_t)gr * DIN + gc] = acc[fm][fn][reg];
      }
    }
}

// ---------------------------------------------------------------------------
// K5: support_bf16[i][j] = bf16( d[i]*(sum of SPLITK partials) + d[i]^2*x )
// ---------------------------------------------------------------------------
__global__ __launch_bounds__(256) void k_combine(
    const float* __restrict__ part, const float* __restrict__ d,
    const float* __restrict__ x, bf16_t* __restrict__ supB) {
  int idx = blockIdx.x * 256 + threadIdx.x;   // float4 index
  int i = idx >> 7;                           // 128 f4 per row
  float4 p = *(const float4*)(part + (size_t)idx * 4);
#pragma unroll
  for (int kc = 1; kc < SPLITK; ++kc) {
    float4 q = *(const float4*)(part + (size_t)kc * NN * DIN + (size_t)idx * 4);
    p.x += q.x; p.y += q.y; p.z += q.z; p.w += q.w;
  }
  float4 xv = *(const float4*)(x + (size_t)idx * 4);
  float di = d[i];
  float dii = di * di;
  bf16x4v o;
  o[0] = (bf16_t)(di * p.x + dii * xv.x);
  o[1] = (bf16_t)(di * p.y + dii * xv.y);
  o[2] = (bf16_t)(di * p.z + dii * xv.z);
  o[3] = (bf16_t)(di * p.w + dii * xv.w);
  *(bf16x4v*)(supB + (size_t)idx * 4) = o;
}

// ---------------------------------------------------------------------------
// K6: out = relu(supB @ Wb^T + bias), fp32 out.
// ---------------------------------------------------------------------------
__global__ __launch_bounds__(256) void k_gemm2(
    const bf16_t* __restrict__ supB, const bf16_t* __restrict__ Wb,
    const float* __restrict__ bias, float* __restrict__ outp) {
  __shared__ bf16_t As[128 * 64];
  __shared__ bf16_t Bs[128 * 64];
  f32x16 acc[2][2];
#pragma unroll
  for (int a = 0; a < 2; ++a)
#pragma unroll
    for (int b = 0; b < 2; ++b)
#pragma unroll
      for (int r = 0; r < 16; ++r) acc[a][b][r] = 0.f;

  const int m0 = blockIdx.x * 128, n0 = blockIdx.y * 128;
  gemm_tile_128x128(supB, Wb, DIN, DIN, m0, n0, 0, DIN, As, Bs, acc);

  const int t = threadIdx.x;
  const int lane = t & 63, wid = t >> 6;
  const int wm = wid >> 1, wn = wid & 1;
  const int l32 = lane & 31, half = lane >> 5;
#pragma unroll
  for (int fn = 0; fn < 2; ++fn) {
    int gc = n0 + wn * 64 + fn * 32 + l32;
    float bb = bias[gc];
#pragma unroll
    for (int fm = 0; fm < 2; ++fm)
#pragma unroll
      for (int reg = 0; reg < 16; ++reg) {
        int gr = m0 + wm * 64 + fm * 32 + (reg & 3) + 8 * (reg >> 2) + 4 * half;
        float v = acc[fm][fn][reg] + bb;
        outp[(size_t)gr * DOUT + gc] = v > 0.f ? v : 0.f;
      }
  }
}

// ---------------------------------------------------------------------------
extern "C" void kernel_launch(void* const* d_in, const int* in_sizes, int n_in,
                              void* d_out, int out_size, void* d_ws, size_t ws_size,
                              hipStream_t stream) {
  const float* x   = (const float*)d_in[0];   // (8192, 512)
  const float* adj = (const float*)d_in[1];   // (8192, 8192)
  const float* W   = (const float*)d_in[2];   // (512, 512) (out,in)
  const float* b   = (const float*)d_in[3];   // (512,)
  float* out = (float*)d_out;                 // (8192, 512) fp32

  char* ws = (char*)d_ws;
  bf16_t* adjb = (bf16_t*)(ws);                        // 134217728 (8192x8192 bf16)
  float*  part = (float*)(ws + 134217728);             // SPLITK x 16 MB fp32
  size_t  off  = 134217728 + (size_t)SPLITK * NN * DIN * 4;
  bf16_t* xsT  = (bf16_t*)(ws + off);                  // 8 MB (512x8192 bf16)
  bf16_t* supB = (bf16_t*)(ws + off + 8388608);        // 8 MB (8192x512 bf16)
  bf16_t* Wb   = (bf16_t*)(ws + off + 16777216);       // 0.5 MB
  float*  dvec = (float*)(ws + off + 17301504);        // 32 KB

  k_rowsum_convert<<<NN, 256, 0, stream>>>(adj, adjb, dvec);
  k_make_xsT<<<dim3(NN / 64, DIN / 64), 256, 0, stream>>>(x, dvec, xsT);
  k_convert_w<<<(DOUT * DIN) / 1024, 256, 0, stream>>>(W, Wb);
  k_gemm1<<<dim3(NN / 128, DIN / 128, SPLITK), 256, 0, stream>>>(adjb, xsT, part);
  k_combine<<<(NN * DIN) / 1024, 256, 0, stream>>>(part, dvec, x, supB);
  k_gemm2<<<dim3(NN / 128, DOUT / 128), 256, 0, stream>>>(supB, Wb, b, out);
}